// Round 5
// baseline (622.054 us; speedup 1.0000x reference)
//
#include <hip/hip_runtime.h>
#include <hip/hip_bf16.h>
#include <cstdint>

#define T_TOK 4096
#define DMODEL 1024
#define HDIM 2048

typedef short bf16x8 __attribute__((ext_vector_type(8)));
typedef float f32x4 __attribute__((ext_vector_type(4)));
typedef uint32_t u32x4 __attribute__((ext_vector_type(4)));

__device__ __forceinline__ uint32_t cvt_pk_bf16(float lo, float hi) {
  uint32_t d;
  asm("v_cvt_pk_bf16_f32 %0, %1, %2" : "=v"(d) : "v"(lo), "v"(hi));
  return d;
}
__device__ __forceinline__ unsigned short f2bf(float f) {
  uint32_t d;
  asm("v_cvt_pk_bf16_f32 %0, %1, %1" : "=v"(d) : "v"(f));
  return (unsigned short)d;
}
// fast exact-erf GELU: Abramowitz-Stegun 7.1.26, |err| <= 1.5e-7
__device__ __forceinline__ float gelu_fast(float v) {
  float z = v * 0.70710678118654752f;
  float az = fabsf(z);
  float t = __frcp_rn(1.0f + 0.3275911f * az);
  float poly = ((((1.061405429f * t - 1.453152027f) * t + 1.421413741f) * t
                 - 0.284496736f) * t + 0.254829592f) * t;
  float er = 1.0f - poly * __expf(-z * z);
  er = (z < 0.f) ? -er : er;
  return 0.5f * v * (1.0f + er);
}
__device__ __forceinline__ void gload16(const void* g, void* lds) {
  __builtin_amdgcn_global_load_lds((const __attribute__((address_space(1))) void*)g,
                                   (__attribute__((address_space(3))) void*)lds, 16, 0, 0);
}
__device__ __forceinline__ u32x4 pk8(const float* s) {
  float4 v0 = ((const float4*)s)[0], v1 = ((const float4*)s)[1];
  u32x4 p = {cvt_pk_bf16(v0.x, v0.y), cvt_pk_bf16(v0.z, v0.w),
             cvt_pk_bf16(v1.x, v1.y), cvt_pk_bf16(v1.z, v1.w)};
  return p;
}
__device__ __forceinline__ u32x4 pk2(float4 a, float4 b) {
  u32x4 p = {cvt_pk_bf16(a.x, a.y), cvt_pk_bf16(a.z, a.w),
             cvt_pk_bf16(b.x, b.y), cvt_pk_bf16(b.z, b.w)};
  return p;
}

// ---------------- router: one wave per token; also emits xb (bf16 x) ----------------
__global__ __launch_bounds__(256) void router_kernel(
    const float* __restrict__ x, const float* __restrict__ Wr,
    int* __restrict__ cursor, int* __restrict__ cnt1,
    float* __restrict__ psum, int* __restrict__ perm, float* __restrict__ pw,
    short* __restrict__ xb) {
  __shared__ float4 sW[8 * 256];
  __shared__ float sP[8];
  int tid = threadIdx.x;
  const float4* W4 = (const float4*)Wr;
  for (int i = tid; i < 2048; i += 256) sW[i] = W4[i];
  if (tid < 8) sP[tid] = 0.f;
  __syncthreads();

  int lane = tid & 63, wid = tid >> 6;
  int t = blockIdx.x * 4 + wid;
  float acc[8] = {0.f, 0.f, 0.f, 0.f, 0.f, 0.f, 0.f, 0.f};
  const float4* x4 = (const float4*)(x + (size_t)t * DMODEL);
#pragma unroll
  for (int it = 0; it < 4; ++it) {
    float4 xv = x4[it * 64 + lane];
    uint2 pk = {cvt_pk_bf16(xv.x, xv.y), cvt_pk_bf16(xv.z, xv.w)};
    *(uint2*)(xb + (size_t)t * DMODEL + it * 256 + lane * 4) = pk;
#pragma unroll
    for (int e = 0; e < 8; ++e) {
      float4 wv = sW[e * 256 + it * 64 + lane];
      acc[e] += xv.x * wv.x + xv.y * wv.y + xv.z * wv.z + xv.w * wv.w;
    }
  }
#pragma unroll
  for (int e = 0; e < 8; ++e)
    for (int off = 32; off; off >>= 1) acc[e] += __shfl_xor(acc[e], off);

  float mx = acc[0];
#pragma unroll
  for (int e = 1; e < 8; ++e) mx = fmaxf(mx, acc[e]);
  float ex[8], s = 0.f;
#pragma unroll
  for (int e = 0; e < 8; ++e) { ex[e] = expf(acc[e] - mx); s += ex[e]; }
  float inv = 1.f / s;
  int e0 = 0;
#pragma unroll
  for (int e = 1; e < 8; ++e) if (acc[e] > acc[e0]) e0 = e;
  int e1 = (e0 == 0) ? 1 : 0;
#pragma unroll
  for (int e = 0; e < 8; ++e) if (e != e0 && acc[e] > acc[e1]) e1 = e;

  if (lane == 0) {
#pragma unroll
    for (int e = 0; e < 8; ++e) atomicAdd(&sP[e], ex[e] * inv);
    atomicAdd(&cnt1[e0], 1);
    int s0 = atomicAdd(&cursor[e0], 1);
    perm[e0 * 4096 + s0] = t; pw[e0 * 4096 + s0] = ex[e0] * inv;
    int s1 = atomicAdd(&cursor[e1], 1);
    perm[e1 * 4096 + s1] = t; pw[e1 * 4096 + s1] = ex[e1] * inv;
  }
  __syncthreads();
  if (tid < 8) atomicAdd(&psum[tid], sP[tid]);
}

// ------------- finalize: padded bases + worklist + aux loss -------------
__global__ void finalize_kernel(const int* __restrict__ cursor,
                                const int* __restrict__ cnt1,
                                const float* __restrict__ psum,
                                int* __restrict__ base, int* __restrict__ work,
                                int* __restrict__ nwork, float* __restrict__ aux_out) {
  if (threadIdx.x == 0) {
    int b = 0, n = 0;
    for (int e = 0; e < 9; ++e) {
      int c = (e < 8) ? cursor[e] : 4096;
      base[e] = b;
      int ntl = (c + 127) >> 7;
      for (int mt = 0; mt < ntl; ++mt) work[n++] = (e << 8) | mt;
      b += ntl << 7;
    }
    *nwork = n;
    float aux = 0.f;
    for (int e = 0; e < 8; ++e)
      aux += ((float)cnt1[e] * (1.f / T_TOK)) * (psum[e] * (1.f / T_TOK));
    aux_out[0] = 0.01f * 8.f * aux;
  }
}

// ---- fused up+gate GEMM: worklist grid, A via gload_lds, B reg-staged f32->bf16 ----
__global__ __launch_bounds__(256, 2) void gemm_upgate(
    const short* __restrict__ xb,
    const float* __restrict__ w1, const float* __restrict__ w3,
    const float* __restrict__ w1s, const float* __restrict__ w3s,
    const int* __restrict__ cursor, const int* __restrict__ base,
    const int* __restrict__ work, const int* __restrict__ nwork,
    const int* __restrict__ perm, unsigned short* __restrict__ hbuf) {
  int y = blockIdx.y;
  if (y >= *nwork) return;
  int wk = work[y];
  int e = wk >> 8, mt = wk & 255, nt = blockIdx.x;
  int cnt = (e < 8) ? cursor[e] : 4096;
  int hb = base[e];
  const float* B1 = (e < 8) ? w1 + (size_t)e * 2097152 : w1s;
  const float* B3 = (e < 8) ? w3 + (size_t)e * 2097152 : w3s;

  __shared__ short As[2][4096], Bs1[2][4096], Bs3[2][4096];

  int tid = threadIdx.x, lane = tid & 63, wid = tid >> 6;
  int fr = lane & 15, ko8 = (lane >> 4) * 8;
  int wr = wid >> 1, wc = wid & 1;

  // A: fragment-major [group g=0..7][lane][8], group g holds rows mt*128+g*16+fr
  size_t aOff[2];
#pragma unroll
  for (int s = 0; s < 2; ++s) {
    int g = s * 4 + wid;
    int slot = mt * 128 + g * 16 + fr;
    int tok = (e == 8) ? slot : ((slot < cnt) ? perm[e * 4096 + slot] : 0);
    aOff[s] = (size_t)tok * DMODEL + ko8;
  }
  // B: slot = s*256+tid -> gg = slot>>6, l = slot&63; row nt*128+gg*16+(l&15), col (l>>4)*8
  const float* bSrc1[2]; const float* bSrc3[2];
#pragma unroll
  for (int s = 0; s < 2; ++s) {
    int slot = s * 256 + tid;
    int gg = slot >> 6, l = slot & 63;
    size_t ro = (size_t)(nt * 128 + gg * 16 + (l & 15)) * DMODEL + ((l >> 4) * 8);
    bSrc1[s] = B1 + ro; bSrc3[s] = B3 + ro;
  }

  f32x4 acc1[4][4] = {}, acc3[4][4] = {};

  auto compute = [&](int buf) {
    bf16x8 af[4], b1f[4], b3f[4];
#pragma unroll
    for (int m = 0; m < 4; ++m)
      af[m] = *(const bf16x8*)&As[buf][(wr * 4 + m) * 512 + lane * 8];
#pragma unroll
    for (int n = 0; n < 4; ++n) {
      b1f[n] = *(const bf16x8*)&Bs1[buf][(wc * 4 + n) * 512 + lane * 8];
      b3f[n] = *(const bf16x8*)&Bs3[buf][(wc * 4 + n) * 512 + lane * 8];
    }
    __builtin_amdgcn_s_setprio(1);
#pragma unroll
    for (int m = 0; m < 4; ++m)
#pragma unroll
      for (int n = 0; n < 4; ++n) {
        acc1[m][n] = __builtin_amdgcn_mfma_f32_16x16x32_bf16(af[m], b1f[n], acc1[m][n], 0, 0, 0);
        acc3[m][n] = __builtin_amdgcn_mfma_f32_16x16x32_bf16(af[m], b3f[n], acc3[m][n], 0, 0, 0);
      }
    __builtin_amdgcn_s_setprio(0);
  };

  // prologue: tile 0
#pragma unroll
  for (int s = 0; s < 2; ++s)
    gload16(xb + aOff[s], &As[0][(s * 4 + wid) * 512 + lane * 8]);
#pragma unroll
  for (int s = 0; s < 2; ++s) {
    int slot = s * 256 + tid;
    *(u32x4*)&Bs1[0][slot * 8] = pk8(bSrc1[s]);
    *(u32x4*)&Bs3[0][slot * 8] = pk8(bSrc3[s]);
  }
  __syncthreads();

  int buf = 0;
#pragma unroll 1
  for (int it = 0; it < 32; ++it) {
    int nx = it + 1;
    float4 r1a[2], r1b[2], r3a[2], r3b[2];
    if (nx < 32) {
#pragma unroll
      for (int s = 0; s < 2; ++s)
        gload16(xb + aOff[s] + nx * 32, &As[buf ^ 1][(s * 4 + wid) * 512 + lane * 8]);
#pragma unroll
      for (int s = 0; s < 2; ++s) {
        const float4* p1 = (const float4*)(bSrc1[s] + nx * 32);
        const float4* p3 = (const float4*)(bSrc3[s] + nx * 32);
        r1a[s] = p1[0]; r1b[s] = p1[1];
        r3a[s] = p3[0]; r3b[s] = p3[1];
      }
    }
    compute(buf);
    if (nx < 32) {
#pragma unroll
      for (int s = 0; s < 2; ++s) {
        int slot = s * 256 + tid;
        *(u32x4*)&Bs1[buf ^ 1][slot * 8] = pk2(r1a[s], r1b[s]);
        *(u32x4*)&Bs3[buf ^ 1][slot * 8] = pk2(r3a[s], r3b[s]);
      }
      __syncthreads();
      buf ^= 1;
    }
  }

  int q = lane >> 4;
#pragma unroll
  for (int m = 0; m < 4; ++m) {
#pragma unroll
    for (int n = 0; n < 4; ++n) {
      int col = nt * 128 + wc * 64 + n * 16 + fr;
      f32x4 u = acc1[m][n], g = acc3[m][n];
#pragma unroll
      for (int j = 0; j < 4; ++j) {
        int sl = mt * 128 + wr * 64 + m * 16 + q * 4 + j;
        float hv = (sl < cnt) ? gelu_fast(u[j]) * g[j] : 0.f;
        hbuf[(size_t)(hb + sl) * HDIM + col] = f2bf(hv);
      }
    }
  }
}

// ---- down GEMM: worklist grid, A via gload_lds, B reg-staged f32->bf16, scatter ----
__global__ __launch_bounds__(256, 3) void gemm_down(
    const unsigned short* __restrict__ hbuf,
    const float* __restrict__ w2, const float* __restrict__ w2s,
    const int* __restrict__ cursor, const int* __restrict__ base,
    const int* __restrict__ work, const int* __restrict__ nwork,
    const int* __restrict__ perm, const float* __restrict__ pw,
    float* __restrict__ out) {
  int y = blockIdx.y;
  if (y >= *nwork) return;
  int wk = work[y];
  int e = wk >> 8, mt = wk & 255, nt = blockIdx.x;
  int cnt = (e < 8) ? cursor[e] : 4096;
  int hb = base[e];
  const float* B = (e < 8) ? w2 + (size_t)e * 2097152 : w2s;

  __shared__ short As[2][4096], Bs[2][4096];

  int tid = threadIdx.x, lane = tid & 63, wid = tid >> 6;
  int fr = lane & 15, ko8 = (lane >> 4) * 8;
  int wr = wid >> 1, wc = wid & 1;

  size_t aOff[2];
#pragma unroll
  for (int s = 0; s < 2; ++s) {
    int g = s * 4 + wid;
    aOff[s] = (size_t)(hb + mt * 128 + g * 16 + fr) * HDIM + ko8;
  }
  const float* bSrc[2];
#pragma unroll
  for (int s = 0; s < 2; ++s) {
    int slot = s * 256 + tid;
    int gg = slot >> 6, l = slot & 63;
    bSrc[s] = B + (size_t)(nt * 128 + gg * 16 + (l & 15)) * HDIM + ((l >> 4) * 8);
  }

  f32x4 acc[4][4] = {};

  auto compute = [&](int buf) {
    bf16x8 af[4], bf[4];
#pragma unroll
    for (int m = 0; m < 4; ++m)
      af[m] = *(const bf16x8*)&As[buf][(wr * 4 + m) * 512 + lane * 8];
#pragma unroll
    for (int n = 0; n < 4; ++n)
      bf[n] = *(const bf16x8*)&Bs[buf][(wc * 4 + n) * 512 + lane * 8];
    __builtin_amdgcn_s_setprio(1);
#pragma unroll
    for (int m = 0; m < 4; ++m)
#pragma unroll
      for (int n = 0; n < 4; ++n)
        acc[m][n] = __builtin_amdgcn_mfma_f32_16x16x32_bf16(af[m], bf[n], acc[m][n], 0, 0, 0);
    __builtin_amdgcn_s_setprio(0);
  };

#pragma unroll
  for (int s = 0; s < 2; ++s)
    gload16(hbuf + aOff[s], &As[0][(s * 4 + wid) * 512 + lane * 8]);
#pragma unroll
  for (int s = 0; s < 2; ++s) {
    int slot = s * 256 + tid;
    *(u32x4*)&Bs[0][slot * 8] = pk8(bSrc[s]);
  }
  __syncthreads();

  int buf = 0;
#pragma unroll 1
  for (int it = 0; it < 64; ++it) {
    int nx = it + 1;
    float4 ra[2], rb[2];
    if (nx < 64) {
#pragma unroll
      for (int s = 0; s < 2; ++s)
        gload16(hbuf + aOff[s] + nx * 32, &As[buf ^ 1][(s * 4 + wid) * 512 + lane * 8]);
#pragma unroll
      for (int s = 0; s < 2; ++s) {
        const float4* p = (const float4*)(bSrc[s] + nx * 32);
        ra[s] = p[0]; rb[s] = p[1];
      }
    }
    compute(buf);
    if (nx < 64) {
#pragma unroll
      for (int s = 0; s < 2; ++s) {
        int slot = s * 256 + tid;
        *(u32x4*)&Bs[buf ^ 1][slot * 8] = pk2(ra[s], rb[s]);
      }
      __syncthreads();
      buf ^= 1;
    }
  }

  int q = lane >> 4;
#pragma unroll
  for (int m = 0; m < 4; ++m) {
#pragma unroll
    for (int n = 0; n < 4; ++n) {
      int col = nt * 128 + wc * 64 + n * 16 + fr;
      f32x4 a = acc[m][n];
#pragma unroll
      for (int j = 0; j < 4; ++j) {
        int sl = mt * 128 + wr * 64 + m * 16 + q * 4 + j;
        if (sl < cnt) {
          int tok; float p;
          if (e == 8) { tok = sl; p = 1.f; }
          else { tok = perm[e * 4096 + sl]; p = pw[e * 4096 + sl]; }
          atomicAdd(&out[(size_t)tok * DMODEL + col], p * a[j]);
        }
      }
    }
  }
}

extern "C" void kernel_launch(void* const* d_in, const int* in_sizes, int n_in,
                              void* d_out, int out_size, void* d_ws, size_t ws_size,
                              hipStream_t stream) {
  const float* x   = (const float*)d_in[0];
  const float* Wr  = (const float*)d_in[1];
  const float* w1  = (const float*)d_in[2];
  const float* w2  = (const float*)d_in[3];
  const float* w3  = (const float*)d_in[4];
  const float* w1s = (const float*)d_in[5];
  const float* w2s = (const float*)d_in[6];
  const float* w3s = (const float*)d_in[7];
  float* out = (float*)d_out;

  char* ws = (char*)d_ws;
  const size_t HBUF_OFF = 0;                       // up to 13312*2048 bf16
  const size_t XB_OFF   = 67108864;                // 4096*1024 bf16
  const size_t PERM_OFF = XB_OFF + 8388608;        // 8*4096 int
  const size_t PW_OFF   = PERM_OFF + 131072;
  const size_t CTRL_OFF = PW_OFF + 131072;         // 256 B: cursor/cnt1/psum/base
  const size_t WORK_OFF = CTRL_OFF + 256;          // 128 ints + nwork

  unsigned short* hbuf = (unsigned short*)(ws + HBUF_OFF);
  short* xb = (short*)(ws + XB_OFF);
  int*   perm   = (int*)(ws + PERM_OFF);
  float* pw     = (float*)(ws + PW_OFF);
  int*   cursor = (int*)(ws + CTRL_OFF);
  int*   cnt1   = (int*)(ws + CTRL_OFF + 64);
  float* psum   = (float*)(ws + CTRL_OFF + 128);
  int*   base   = (int*)(ws + CTRL_OFF + 192);
  int*   work   = (int*)(ws + WORK_OFF);
  int*   nwork  = (int*)(ws + WORK_OFF + 512);

  hipMemsetAsync(d_out, 0, (size_t)out_size * sizeof(float), stream);
  hipMemsetAsync(ws + CTRL_OFF, 0, 256, stream);

  router_kernel<<<1024, 256, 0, stream>>>(x, Wr, cursor, cnt1, psum, perm, pw, xb);
  finalize_kernel<<<1, 64, 0, stream>>>(cursor, cnt1, psum, base, work, nwork,
                                        out + (size_t)T_TOK * DMODEL);
  gemm_upgate<<<dim3(16, 128), 256, 0, stream>>>(xb, w1, w3, w1s, w3s,
                                                 cursor, base, work, nwork, perm, hbuf);
  gemm_down<<<dim3(8, 128), 256, 0, stream>>>(hbuf, w2, w2s,
                                              cursor, base, work, nwork, perm, pw, out);
}

// Round 6
// 482.834 us; speedup vs baseline: 1.2883x; 1.2883x over previous
//
#include <hip/hip_runtime.h>
#include <hip/hip_bf16.h>
#include <cstdint>

#define T_TOK 4096
#define DMODEL 1024
#define HDIM 2048

typedef short bf16x8 __attribute__((ext_vector_type(8)));
typedef float f32x4 __attribute__((ext_vector_type(4)));
typedef uint32_t u32x4 __attribute__((ext_vector_type(4)));

#define WAITVM(N) asm volatile("s_waitcnt vmcnt(" #N ")" ::: "memory")
#define BARX() asm volatile("s_barrier" ::: "memory")

__device__ __forceinline__ uint32_t cvt_pk_bf16(float lo, float hi) {
  uint32_t d;
  asm("v_cvt_pk_bf16_f32 %0, %1, %2" : "=v"(d) : "v"(lo), "v"(hi));
  return d;
}
__device__ __forceinline__ unsigned short f2bf(float f) {
  uint32_t d;
  asm("v_cvt_pk_bf16_f32 %0, %1, %1" : "=v"(d) : "v"(f));
  return (unsigned short)d;
}
// fast exact-erf GELU: Abramowitz-Stegun 7.1.26, |err| <= 1.5e-7
__device__ __forceinline__ float gelu_fast(float v) {
  float z = v * 0.70710678118654752f;
  float az = fabsf(z);
  float t = __frcp_rn(1.0f + 0.3275911f * az);
  float poly = ((((1.061405429f * t - 1.453152027f) * t + 1.421413741f) * t
                 - 0.284496736f) * t + 0.254829592f) * t;
  float er = 1.0f - poly * __expf(-z * z);
  er = (z < 0.f) ? -er : er;
  return 0.5f * v * (1.0f + er);
}
__device__ __forceinline__ void gload16(const void* g, void* lds) {
  __builtin_amdgcn_global_load_lds((const __attribute__((address_space(1))) void*)g,
                                   (__attribute__((address_space(3))) void*)lds, 16, 0, 0);
}
__device__ __forceinline__ u32x4 pk8(const float* s) {
  float4 v0 = ((const float4*)s)[0], v1 = ((const float4*)s)[1];
  u32x4 p = {cvt_pk_bf16(v0.x, v0.y), cvt_pk_bf16(v0.z, v0.w),
             cvt_pk_bf16(v1.x, v1.y), cvt_pk_bf16(v1.z, v1.w)};
  return p;
}

// ---------------- conversions (fragment-major bf16) ----------------
// wB per expert (upgate, u/g col-interleaved): [nf:256][k32:32][lane:64][8]
//   nf even -> w1 cols, nf odd -> w3 cols; h = (nf>>1)*16 + (lane&15)
// wd per expert (down): [d16:64][h32:64][lane:64][8]
__global__ __launch_bounds__(256) void convert_w(
    const float* __restrict__ w1, const float* __restrict__ w3,
    const float* __restrict__ w1s, const float* __restrict__ w3s,
    const float* __restrict__ w2, const float* __restrict__ w2s,
    short* __restrict__ wB, short* __restrict__ wd) {
  int bid = blockIdx.x;
  if (bid < 18432) {
    int id = bid * 256 + threadIdx.x;      // 9*256*32*64 = 4718592 chunks
    int e = id >> 19, rem = id & 524287;
    int nf = rem >> 11, k32 = (rem >> 6) & 31, ln = rem & 63;
    int h = (nf >> 1) * 16 + (ln & 15);
    size_t so = (size_t)h * DMODEL + k32 * 32 + (ln >> 4) * 8;
    const float* src = (nf & 1)
        ? ((e < 8) ? w3 + (size_t)e * 2097152 + so : w3s + so)
        : ((e < 8) ? w1 + (size_t)e * 2097152 + so : w1s + so);
    *(u32x4*)(wB + (size_t)id * 8) = pk8(src);
  } else {
    int id = (bid - 18432) * 256 + threadIdx.x;   // 9*64*64*64 = 2359296 chunks
    int e = id >> 18, rem = id & 262143;
    int d16 = rem >> 12, h32 = (rem >> 6) & 63, ln = rem & 63;
    size_t so = (size_t)(d16 * 16 + (ln & 15)) * HDIM + h32 * 32 + (ln >> 4) * 8;
    const float* s2 = (e < 8) ? w2 + (size_t)e * 2097152 + so : w2s + so;
    *(u32x4*)(wd + (size_t)id * 8) = pk8(s2);
  }
}

// ---------------- router: one wave per token; also emits xb (bf16 x) ----------------
__global__ __launch_bounds__(256) void router_kernel(
    const float* __restrict__ x, const float* __restrict__ Wr,
    int* __restrict__ cursor, int* __restrict__ cnt1,
    float* __restrict__ psum, int* __restrict__ perm, float* __restrict__ pw,
    short* __restrict__ xb) {
  __shared__ float4 sW[8 * 256];
  __shared__ float sP[8];
  int tid = threadIdx.x;
  const float4* W4 = (const float4*)Wr;
  for (int i = tid; i < 2048; i += 256) sW[i] = W4[i];
  if (tid < 8) sP[tid] = 0.f;
  __syncthreads();

  int lane = tid & 63, wid = tid >> 6;
  int t = blockIdx.x * 4 + wid;
  float acc[8] = {0.f, 0.f, 0.f, 0.f, 0.f, 0.f, 0.f, 0.f};
  const float4* x4 = (const float4*)(x + (size_t)t * DMODEL);
#pragma unroll
  for (int it = 0; it < 4; ++it) {
    float4 xv = x4[it * 64 + lane];
    uint2 pk = {cvt_pk_bf16(xv.x, xv.y), cvt_pk_bf16(xv.z, xv.w)};
    *(uint2*)(xb + (size_t)t * DMODEL + it * 256 + lane * 4) = pk;
#pragma unroll
    for (int e = 0; e < 8; ++e) {
      float4 wv = sW[e * 256 + it * 64 + lane];
      acc[e] += xv.x * wv.x + xv.y * wv.y + xv.z * wv.z + xv.w * wv.w;
    }
  }
#pragma unroll
  for (int e = 0; e < 8; ++e)
    for (int off = 32; off; off >>= 1) acc[e] += __shfl_xor(acc[e], off);

  float mx = acc[0];
#pragma unroll
  for (int e = 1; e < 8; ++e) mx = fmaxf(mx, acc[e]);
  float ex[8], s = 0.f;
#pragma unroll
  for (int e = 0; e < 8; ++e) { ex[e] = expf(acc[e] - mx); s += ex[e]; }
  float inv = 1.f / s;
  int e0 = 0;
#pragma unroll
  for (int e = 1; e < 8; ++e) if (acc[e] > acc[e0]) e0 = e;
  int e1 = (e0 == 0) ? 1 : 0;
#pragma unroll
  for (int e = 0; e < 8; ++e) if (e != e0 && acc[e] > acc[e1]) e1 = e;

  if (lane == 0) {
#pragma unroll
    for (int e = 0; e < 8; ++e) atomicAdd(&sP[e], ex[e] * inv);
    atomicAdd(&cnt1[e0], 1);
    int s0 = atomicAdd(&cursor[e0], 1);
    perm[e0 * 4096 + s0] = t; pw[e0 * 4096 + s0] = ex[e0] * inv;
    int s1 = atomicAdd(&cursor[e1], 1);
    perm[e1 * 4096 + s1] = t; pw[e1 * 4096 + s1] = ex[e1] * inv;
  }
  __syncthreads();
  if (tid < 8) atomicAdd(&psum[tid], sP[tid]);
}

// ------- finalize: 256-aligned bases + two worklists + aux loss -------
__global__ void finalize_kernel(const int* __restrict__ cursor,
                                const int* __restrict__ cnt1,
                                const float* __restrict__ psum,
                                int* __restrict__ base,
                                int* __restrict__ work256, int* __restrict__ work128,
                                int* __restrict__ n256, int* __restrict__ n128,
                                float* __restrict__ aux_out) {
  if (threadIdx.x == 0) {
    int b = 0, a = 0, c2 = 0;
    for (int e = 0; e < 9; ++e) {
      int c = (e < 8) ? cursor[e] : 4096;
      base[e] = b;
      int t2 = (c + 255) >> 8;
      for (int mt = 0; mt < t2; ++mt) work256[a++] = (e << 8) | mt;
      int t1 = (c + 127) >> 7;
      for (int mt = 0; mt < t1; ++mt) work128[c2++] = (e << 8) | mt;
      b += t2 << 8;
    }
    *n256 = a; *n128 = c2;
    float aux = 0.f;
    for (int e = 0; e < 8; ++e)
      aux += ((float)cnt1[e] * (1.f / T_TOK)) * (psum[e] * (1.f / T_TOK));
    aux_out[0] = 0.01f * 8.f * aux;
  }
}

// ---------------- 8-phase 256x256 up+gate GEMM (interleaved u/g B) ----------------
template<int MH>
__device__ __forceinline__ void quad(const short* __restrict__ sA,
                                     const short* __restrict__ sB,
                                     f32x4 (&acc)[8][4], int wm, int wn, int lane) {
  bf16x8 af[4], bf[4];
#pragma unroll
  for (int i = 0; i < 4; ++i)
    af[i] = *(const bf16x8*)&sA[(wm * 8 + MH * 4 + i) * 512 + lane * 8];
#pragma unroll
  for (int n = 0; n < 4; ++n)
    bf[n] = *(const bf16x8*)&sB[(wn * 4 + n) * 512 + lane * 8];
  BARX();
  __builtin_amdgcn_s_setprio(1);
#pragma unroll
  for (int i = 0; i < 4; ++i)
#pragma unroll
    for (int n = 0; n < 4; ++n)
      acc[MH * 4 + i][n] =
          __builtin_amdgcn_mfma_f32_16x16x32_bf16(af[i], bf[n], acc[MH * 4 + i][n], 0, 0, 0);
  __builtin_amdgcn_s_setprio(0);
  BARX();
}

__global__ __launch_bounds__(512) void gemm_upgate8(
    const short* __restrict__ xb, const short* __restrict__ wB,
    const int* __restrict__ cursor, const int* __restrict__ base,
    const int* __restrict__ work, const int* __restrict__ nwork,
    const int* __restrict__ perm, unsigned short* __restrict__ hbuf) {
  int y = blockIdx.y;
  if (y >= *nwork) return;
  int wk = work[y];
  int e = wk >> 8, mt = wk & 255, nt = blockIdx.x;
  int cnt = (e < 8) ? cursor[e] : 4096;
  int hb = base[e];
  const short* wE = wB + (size_t)e * 4194304;

  // LDS: [buf:2][ A(k32=0) 8192 | A(k32=1) 8192 | B(k32=0) 8192 | B(k32=1) 8192 ]
  __shared__ short lds[65536];

  int tid = threadIdx.x, lane = tid & 63, wid = tid >> 6;
  int wm = wid >> 2, wn = wid & 3;
  int fr = lane & 15, q4r = lane >> 4;

  // A sources: thread serves groups g = wid and 8+wid (rows mt*256+g*16+fr)
  size_t aOff[2];
#pragma unroll
  for (int c = 0; c < 2; ++c) {
    int g = c * 8 + wid;
    int slot = mt * 256 + g * 16 + fr;
    int tok = (e == 8) ? slot : ((slot < cnt) ? perm[e * 4096 + slot] : 0);
    aOff[c] = (size_t)tok * DMODEL + q4r * 8;
  }
  // B sources: nf = nt*16 + c*8 + wid
  size_t bOff[2];
#pragma unroll
  for (int c = 0; c < 2; ++c)
    bOff[c] = ((size_t)(nt * 16 + c * 8 + wid) * 32) * 512 + lane * 8;

  auto issueA = [&](int tt, int k32) {
    int db = (tt & 1) * 32768 + k32 * 8192 + tid * 8;
    size_t sk = (size_t)(tt * 64 + k32 * 32);
    gload16(xb + aOff[0] + sk, &lds[db]);
    gload16(xb + aOff[1] + sk, &lds[db + 4096]);
  };
  auto issueB = [&](int tt, int k32) {
    int db = (tt & 1) * 32768 + 16384 + k32 * 8192 + tid * 8;
    size_t sk = (size_t)(tt * 2 + k32) * 512;
    gload16(wE + bOff[0] + sk, &lds[db]);
    gload16(wE + bOff[1] + sk, &lds[db + 4096]);
  };

  f32x4 acc[8][4] = {};

  // prologue: SA0(0) SB0(0) SA1(0) SB1(0) SA0(1) SB0(1)  (12 loads)
  issueA(0, 0); issueB(0, 0);
  issueA(0, 1); issueB(0, 1);
  issueA(1, 0); issueB(1, 0);

#pragma unroll 1
  for (int t = 0; t < 16; ++t) {
    const short* b0 = &lds[(t & 1) * 32768];
    // ---- phases 1,2: k32=0 ----
    if (t == 15) { WAITVM(4); } else { WAITVM(8); }
    BARX();
    if (t < 15) issueA(t + 1, 1);
    quad<0>(b0, b0 + 16384, acc, wm, wn, lane);
    if (t < 15) issueB(t + 1, 1);
    quad<1>(b0, b0 + 16384, acc, wm, wn, lane);
    // ---- phases 3,4: k32=1 ----
    if (t == 15) { WAITVM(0); } else { WAITVM(8); }
    BARX();
    if (t < 14) issueA(t + 2, 0);
    quad<0>(b0 + 8192, b0 + 8192 + 16384, acc, wm, wn, lane);
    if (t < 14) issueB(t + 2, 0);
    quad<1>(b0 + 8192, b0 + 8192 + 16384, acc, wm, wn, lane);
  }

  // epilogue: pair even/odd n-frags (u, g) -> gelu(u)*g
#pragma unroll
  for (int m = 0; m < 8; ++m) {
#pragma unroll
    for (int p = 0; p < 2; ++p) {
      f32x4 u = acc[m][2 * p], g = acc[m][2 * p + 1];
      int hcol = (nt * 8 + wn * 2 + p) * 16 + fr;
#pragma unroll
      for (int j = 0; j < 4; ++j) {
        int sl = mt * 256 + wm * 128 + m * 16 + q4r * 4 + j;
        float hv = (sl < cnt) ? gelu_fast(u[j]) * g[j] : 0.f;
        hbuf[(size_t)(hb + sl) * HDIM + hcol] = f2bf(hv);
      }
    }
  }
}

// ---- down GEMM: 3-deep pipeline, counted vmcnt, weighted scatter (round-4 body) ----
__global__ __launch_bounds__(256, 3) void gemm_down(
    const unsigned short* __restrict__ hbuf,
    const short* __restrict__ wd,
    const int* __restrict__ cursor, const int* __restrict__ base,
    const int* __restrict__ work, const int* __restrict__ nwork,
    const int* __restrict__ perm, const float* __restrict__ pw,
    float* __restrict__ out) {
  int y = blockIdx.y;
  if (y >= *nwork) return;
  int wk = work[y];
  int e = wk >> 8, mt = wk & 255, nt = blockIdx.x;
  int cnt = (e < 8) ? cursor[e] : 4096;
  int hb = base[e];
  const short* wdE = wd + (size_t)e * 2097152;

  __shared__ short As[3][4096], Bs[3][4096];

  int tid = threadIdx.x, lane = tid & 63, wid = tid >> 6;
  int fr = lane & 15, ko8 = (lane >> 4) * 8;
  int wr = wid >> 1, wc = wid & 1;

  size_t aOff[2], bOff[2];
#pragma unroll
  for (int s = 0; s < 2; ++s) {
    int g = s * 4 + wid;
    aOff[s] = (size_t)(hb + mt * 128 + g * 16 + fr) * HDIM + ko8;
    bOff[s] = ((size_t)(nt * 8 + g) * 64 * 64 + lane) * 8;
  }

  f32x4 acc[4][4] = {};

  auto stage = [&](int buf, int it) {   // 4 vmem ops per thread
#pragma unroll
    for (int s = 0; s < 2; ++s) {
      int g = s * 4 + wid;
      gload16(hbuf + aOff[s] + it * 32, &As[buf][g * 512 + lane * 8]);
      gload16(wdE + bOff[s] + (size_t)it * 512, &Bs[buf][g * 512 + lane * 8]);
    }
  };
  auto compute = [&](int buf) {
    bf16x8 af[4], bf[4];
#pragma unroll
    for (int m = 0; m < 4; ++m)
      af[m] = *(const bf16x8*)&As[buf][(wr * 4 + m) * 512 + lane * 8];
#pragma unroll
    for (int n = 0; n < 4; ++n)
      bf[n] = *(const bf16x8*)&Bs[buf][(wc * 4 + n) * 512 + lane * 8];
    __builtin_amdgcn_s_setprio(1);
#pragma unroll
    for (int m = 0; m < 4; ++m)
#pragma unroll
      for (int n = 0; n < 4; ++n)
        acc[m][n] = __builtin_amdgcn_mfma_f32_16x16x32_bf16(af[m], bf[n], acc[m][n], 0, 0, 0);
    __builtin_amdgcn_s_setprio(0);
  };

  stage(0, 0);
  stage(1, 1);
  int cur = 0, pf = 2;
#pragma unroll 1
  for (int it = 0; it < 62; ++it) {
    stage(pf, it + 2);
    WAITVM(8);
    BARX();
    compute(cur);
    BARX();
    pf = cur; cur = (cur == 2) ? 0 : cur + 1;
  }
  WAITVM(4); BARX(); compute(cur); BARX();
  cur = (cur == 2) ? 0 : cur + 1;
  WAITVM(0); BARX(); compute(cur);

  int q = lane >> 4;
#pragma unroll
  for (int m = 0; m < 4; ++m) {
#pragma unroll
    for (int n = 0; n < 4; ++n) {
      int col = nt * 128 + wc * 64 + n * 16 + fr;
      f32x4 a = acc[m][n];
#pragma unroll
      for (int j = 0; j < 4; ++j) {
        int sl = mt * 128 + wr * 64 + m * 16 + q * 4 + j;
        if (sl < cnt) {
          int tok; float p;
          if (e == 8) { tok = sl; p = 1.f; }
          else { tok = perm[e * 4096 + sl]; p = pw[e * 4096 + sl]; }
          atomicAdd(&out[(size_t)tok * DMODEL + col], p * a[j]);
        }
      }
    }
  }
}

extern "C" void kernel_launch(void* const* d_in, const int* in_sizes, int n_in,
                              void* d_out, int out_size, void* d_ws, size_t ws_size,
                              hipStream_t stream) {
  const float* x   = (const float*)d_in[0];
  const float* Wr  = (const float*)d_in[1];
  const float* w1  = (const float*)d_in[2];
  const float* w2  = (const float*)d_in[3];
  const float* w3  = (const float*)d_in[4];
  const float* w1s = (const float*)d_in[5];
  const float* w2s = (const float*)d_in[6];
  const float* w3s = (const float*)d_in[7];
  float* out = (float*)d_out;

  char* ws = (char*)d_ws;
  const size_t HBUF_OFF = 0;                        // <= 14336*2048 bf16 = 58.7 MB
  const size_t XB_OFF   = 67108864;                 // 4096*1024 bf16
  const size_t WB_OFF   = XB_OFF + 8388608;         // 9*4M shorts = 75.5 MB
  const size_t WD_OFF   = WB_OFF + 75497472;        // 9*2M shorts = 37.7 MB
  const size_t PERM_OFF = WD_OFF + 37748736;        // 8*4096 int
  const size_t PW_OFF   = PERM_OFF + 131072;
  const size_t CTRL_OFF = PW_OFF + 131072;          // 256 B
  const size_t W256_OFF = CTRL_OFF + 256;           // 256 ints
  const size_t W128_OFF = W256_OFF + 1024;          // 256 ints

  unsigned short* hbuf = (unsigned short*)(ws + HBUF_OFF);
  short* xb = (short*)(ws + XB_OFF);
  short* wB = (short*)(ws + WB_OFF);
  short* wd = (short*)(ws + WD_OFF);
  int*   perm   = (int*)(ws + PERM_OFF);
  float* pw     = (float*)(ws + PW_OFF);
  int*   cursor = (int*)(ws + CTRL_OFF);
  int*   cnt1   = (int*)(ws + CTRL_OFF + 64);
  float* psum   = (float*)(ws + CTRL_OFF + 128);
  int*   base   = (int*)(ws + CTRL_OFF + 192);      // 9 ints
  int*   n256   = (int*)(ws + CTRL_OFF + 240);
  int*   n128   = (int*)(ws + CTRL_OFF + 244);
  int*   work256 = (int*)(ws + W256_OFF);
  int*   work128 = (int*)(ws + W128_OFF);

  hipMemsetAsync(d_out, 0, (size_t)out_size * sizeof(float), stream);
  hipMemsetAsync(ws + CTRL_OFF, 0, 256, stream);

  router_kernel<<<1024, 256, 0, stream>>>(x, Wr, cursor, cnt1, psum, perm, pw, xb);
  finalize_kernel<<<1, 64, 0, stream>>>(cursor, cnt1, psum, base,
                                        work256, work128, n256, n128,
                                        out + (size_t)T_TOK * DMODEL);
  convert_w<<<27648, 256, 0, stream>>>(w1, w3, w1s, w3s, w2, w2s, wB, wd);
  gemm_upgate8<<<dim3(16, 64), 512, 0, stream>>>(xb, wB, cursor, base,
                                                 work256, n256, perm, hbuf);
  gemm_down<<<dim3(8, 128), 256, 0, stream>>>(hbuf, wd, cursor, base,
                                              work128, n128, perm, pw, out);
}

// Round 7
// 403.284 us; speedup vs baseline: 1.5425x; 1.1973x over previous
//
#include <hip/hip_runtime.h>
#include <hip/hip_bf16.h>
#include <cstdint>

#define T_TOK 4096
#define DMODEL 1024
#define HDIM 2048

typedef short bf16x8 __attribute__((ext_vector_type(8)));
typedef float f32x4 __attribute__((ext_vector_type(4)));
typedef uint32_t u32x4 __attribute__((ext_vector_type(4)));

#define WAITVM(N) asm volatile("s_waitcnt vmcnt(" #N ")" ::: "memory")
#define BARX() asm volatile("s_barrier" ::: "memory")

__device__ __forceinline__ uint32_t cvt_pk_bf16(float lo, float hi) {
  uint32_t d;
  asm("v_cvt_pk_bf16_f32 %0, %1, %2" : "=v"(d) : "v"(lo), "v"(hi));
  return d;
}
__device__ __forceinline__ unsigned short f2bf(float f) {
  uint32_t d;
  asm("v_cvt_pk_bf16_f32 %0, %1, %1" : "=v"(d) : "v"(f));
  return (unsigned short)d;
}
// fast exact-erf GELU: Abramowitz-Stegun 7.1.26, |err| <= 1.5e-7
__device__ __forceinline__ float gelu_fast(float v) {
  float z = v * 0.70710678118654752f;
  float az = fabsf(z);
  float t = __frcp_rn(1.0f + 0.3275911f * az);
  float poly = ((((1.061405429f * t - 1.453152027f) * t + 1.421413741f) * t
                 - 0.284496736f) * t + 0.254829592f) * t;
  float er = 1.0f - poly * __expf(-z * z);
  er = (z < 0.f) ? -er : er;
  return 0.5f * v * (1.0f + er);
}
__device__ __forceinline__ void gload16(const void* g, void* lds) {
  __builtin_amdgcn_global_load_lds((const __attribute__((address_space(1))) void*)g,
                                   (__attribute__((address_space(3))) void*)lds, 16, 0, 0);
}
__device__ __forceinline__ u32x4 pk8(const float* s) {
  float4 v0 = ((const float4*)s)[0], v1 = ((const float4*)s)[1];
  u32x4 p = {cvt_pk_bf16(v0.x, v0.y), cvt_pk_bf16(v0.z, v0.w),
             cvt_pk_bf16(v1.x, v1.y), cvt_pk_bf16(v1.z, v1.w)};
  return p;
}

// ---------------- conversions (fragment-major bf16) ----------------
// wB per expert (upgate, u/g col-interleaved): [nf:256][k32:32][lane:64][8]
// wd per expert (down): [d16:64][h32:64][lane:64][8]
__global__ __launch_bounds__(256) void convert_w(
    const float* __restrict__ w1, const float* __restrict__ w3,
    const float* __restrict__ w1s, const float* __restrict__ w3s,
    const float* __restrict__ w2, const float* __restrict__ w2s,
    short* __restrict__ wB, short* __restrict__ wd) {
  int bid = blockIdx.x;
  if (bid < 18432) {
    int id = bid * 256 + threadIdx.x;
    int e = id >> 19, rem = id & 524287;
    int nf = rem >> 11, k32 = (rem >> 6) & 31, ln = rem & 63;
    int h = (nf >> 1) * 16 + (ln & 15);
    size_t so = (size_t)h * DMODEL + k32 * 32 + (ln >> 4) * 8;
    const float* src = (nf & 1)
        ? ((e < 8) ? w3 + (size_t)e * 2097152 + so : w3s + so)
        : ((e < 8) ? w1 + (size_t)e * 2097152 + so : w1s + so);
    *(u32x4*)(wB + (size_t)id * 8) = pk8(src);
  } else {
    int id = (bid - 18432) * 256 + threadIdx.x;
    int e = id >> 18, rem = id & 262143;
    int d16 = rem >> 12, h32 = (rem >> 6) & 63, ln = rem & 63;
    size_t so = (size_t)(d16 * 16 + (ln & 15)) * HDIM + h32 * 32 + (ln >> 4) * 8;
    const float* s2 = (e < 8) ? w2 + (size_t)e * 2097152 + so : w2s + so;
    *(u32x4*)(wd + (size_t)id * 8) = pk8(s2);
  }
}

// ---------------- router: one wave per token; also emits xb + token routing ------
__global__ __launch_bounds__(256) void router_kernel(
    const float* __restrict__ x, const float* __restrict__ Wr,
    int* __restrict__ cursor, int* __restrict__ cnt1,
    float* __restrict__ psum, int* __restrict__ perm,
    int* __restrict__ tokpos, float* __restrict__ wtok,
    short* __restrict__ xb) {
  __shared__ float4 sW[8 * 256];
  __shared__ float sP[8];
  int tid = threadIdx.x;
  const float4* W4 = (const float4*)Wr;
  for (int i = tid; i < 2048; i += 256) sW[i] = W4[i];
  if (tid < 8) sP[tid] = 0.f;
  __syncthreads();

  int lane = tid & 63, wid = tid >> 6;
  int t = blockIdx.x * 4 + wid;
  float acc[8] = {0.f, 0.f, 0.f, 0.f, 0.f, 0.f, 0.f, 0.f};
  const float4* x4 = (const float4*)(x + (size_t)t * DMODEL);
#pragma unroll
  for (int it = 0; it < 4; ++it) {
    float4 xv = x4[it * 64 + lane];
    uint2 pk = {cvt_pk_bf16(xv.x, xv.y), cvt_pk_bf16(xv.z, xv.w)};
    *(uint2*)(xb + (size_t)t * DMODEL + it * 256 + lane * 4) = pk;
#pragma unroll
    for (int e = 0; e < 8; ++e) {
      float4 wv = sW[e * 256 + it * 64 + lane];
      acc[e] += xv.x * wv.x + xv.y * wv.y + xv.z * wv.z + xv.w * wv.w;
    }
  }
#pragma unroll
  for (int e = 0; e < 8; ++e)
    for (int off = 32; off; off >>= 1) acc[e] += __shfl_xor(acc[e], off);

  float mx = acc[0];
#pragma unroll
  for (int e = 1; e < 8; ++e) mx = fmaxf(mx, acc[e]);
  float ex[8], s = 0.f;
#pragma unroll
  for (int e = 0; e < 8; ++e) { ex[e] = expf(acc[e] - mx); s += ex[e]; }
  float inv = 1.f / s;
  int e0 = 0;
#pragma unroll
  for (int e = 1; e < 8; ++e) if (acc[e] > acc[e0]) e0 = e;
  int e1 = (e0 == 0) ? 1 : 0;
#pragma unroll
  for (int e = 0; e < 8; ++e) if (e != e0 && acc[e] > acc[e1]) e1 = e;

  if (lane == 0) {
#pragma unroll
    for (int e = 0; e < 8; ++e) atomicAdd(&sP[e], ex[e] * inv);
    atomicAdd(&cnt1[e0], 1);
    int s0 = atomicAdd(&cursor[e0], 1);
    perm[e0 * 4096 + s0] = t;
    int s1 = atomicAdd(&cursor[e1], 1);
    perm[e1 * 4096 + s1] = t;
    tokpos[2 * t] = (e0 << 12) | s0;
    tokpos[2 * t + 1] = (e1 << 12) | s1;
    wtok[2 * t] = ex[e0] * inv;
    wtok[2 * t + 1] = ex[e1] * inv;
  }
  __syncthreads();
  if (tid < 8) atomicAdd(&psum[tid], sP[tid]);
}

// ------- finalize: 256-aligned bases + two worklists + aux loss -------
__global__ void finalize_kernel(const int* __restrict__ cursor,
                                const int* __restrict__ cnt1,
                                const float* __restrict__ psum,
                                int* __restrict__ base,
                                int* __restrict__ work256, int* __restrict__ work128,
                                int* __restrict__ n256, int* __restrict__ n128,
                                float* __restrict__ aux_out) {
  if (threadIdx.x == 0) {
    int b = 0, a = 0, c2 = 0;
    for (int e = 0; e < 9; ++e) {
      int c = (e < 8) ? cursor[e] : 4096;
      base[e] = b;
      int t2 = (c + 255) >> 8;
      for (int mt = 0; mt < t2; ++mt) work256[a++] = (e << 8) | mt;
      int t1 = (c + 127) >> 7;
      for (int mt = 0; mt < t1; ++mt) work128[c2++] = (e << 8) | mt;
      b += t2 << 8;
    }
    *n256 = a; *n128 = c2;
    float aux = 0.f;
    for (int e = 0; e < 8; ++e)
      aux += ((float)cnt1[e] * (1.f / T_TOK)) * (psum[e] * (1.f / T_TOK));
    aux_out[0] = 0.01f * 8.f * aux;
  }
}

// ------------ 256x256 up+gate GEMM: one barrier per K-tile, BK=64 ------------
// LDS buf (32768 shorts): A[(k32*16+g)*512+lane*8] (32KB) | B at +16384 same idx.
__global__ __launch_bounds__(512) void gemm_upgate8(
    const short* __restrict__ xb, const short* __restrict__ wB,
    const int* __restrict__ cursor, const int* __restrict__ base,
    const int* __restrict__ work, const int* __restrict__ nwork,
    const int* __restrict__ perm, unsigned short* __restrict__ hbuf) {
  int y = blockIdx.y;
  if (y >= *nwork) return;
  int wk = work[y];
  int e = wk >> 8, mt = wk & 255, nt = blockIdx.x;
  int cnt = (e < 8) ? cursor[e] : 4096;
  int hb = base[e];
  const short* wE = wB + (size_t)e * 4194304;

  __shared__ short lds[65536];

  int tid = threadIdx.x, lane = tid & 63, wid = tid >> 6;
  int wm = wid >> 2, wn = wid & 3;
  int fr = lane & 15, q4r = lane >> 4;

  size_t aOff[2];
#pragma unroll
  for (int c = 0; c < 2; ++c) {
    int g = c * 8 + wid;
    int slot = mt * 256 + g * 16 + fr;
    int tok = (e == 8) ? slot : ((slot < cnt) ? perm[e * 4096 + slot] : 0);
    aOff[c] = (size_t)tok * DMODEL + q4r * 8;
  }
  size_t bOff[2];
#pragma unroll
  for (int c = 0; c < 2; ++c)
    bOff[c] = ((size_t)(nt * 16 + c * 8 + wid) * 32) * 512 + lane * 8;

  auto stageT = [&](int tt) {
    int bb = (tt & 1) * 32768;
#pragma unroll
    for (int c = 0; c < 2; ++c) {
      int g = c * 8 + wid;
#pragma unroll
      for (int k32 = 0; k32 < 2; ++k32) {
        gload16(xb + aOff[c] + tt * 64 + k32 * 32,
                &lds[bb + (k32 * 16 + g) * 512 + lane * 8]);
        gload16(wE + bOff[c] + (size_t)(tt * 2 + k32) * 512,
                &lds[bb + 16384 + (k32 * 16 + g) * 512 + lane * 8]);
      }
    }
  };

  f32x4 acc[8][4] = {};

  stageT(0);
#pragma unroll 1
  for (int t = 0; t < 16; ++t) {
    WAITVM(0);
    BARX();
    if (t < 15) stageT(t + 1);
    const short* bufp = &lds[(t & 1) * 32768];
#pragma unroll
    for (int k32 = 0; k32 < 2; ++k32) {
      bf16x8 af[8], bf[4];
#pragma unroll
      for (int i = 0; i < 8; ++i)
        af[i] = *(const bf16x8*)&bufp[(k32 * 16 + wm * 8 + i) * 512 + lane * 8];
#pragma unroll
      for (int n = 0; n < 4; ++n)
        bf[n] = *(const bf16x8*)&bufp[16384 + (k32 * 16 + wn * 4 + n) * 512 + lane * 8];
      __builtin_amdgcn_s_setprio(1);
#pragma unroll
      for (int i = 0; i < 8; ++i)
#pragma unroll
        for (int n = 0; n < 4; ++n)
          acc[i][n] = __builtin_amdgcn_mfma_f32_16x16x32_bf16(af[i], bf[n], acc[i][n], 0, 0, 0);
      __builtin_amdgcn_s_setprio(0);
    }
  }

  // epilogue: pair even/odd n-frags (u, g) -> gelu(u)*g
#pragma unroll
  for (int m = 0; m < 8; ++m) {
#pragma unroll
    for (int p = 0; p < 2; ++p) {
      f32x4 u = acc[m][2 * p], g = acc[m][2 * p + 1];
      int hcol = (nt * 8 + wn * 2 + p) * 16 + fr;
#pragma unroll
      for (int j = 0; j < 4; ++j) {
        int sl = mt * 256 + wm * 128 + m * 16 + q4r * 4 + j;
        float hv = (sl < cnt) ? gelu_fast(u[j]) * g[j] : 0.f;
        hbuf[(size_t)(hb + sl) * HDIM + hcol] = f2bf(hv);
      }
    }
  }
}

// ------------ down GEMM: 128x128, BK=64, one barrier per K-tile, ybuf out ------
// LDS buf (16384 shorts): A[(k32*8+g)*512+lane*8] (16KB) | B at +8192.
__global__ __launch_bounds__(256, 2) void gemm_down(
    const unsigned short* __restrict__ hbuf,
    const short* __restrict__ wd,
    const int* __restrict__ cursor, const int* __restrict__ base,
    const int* __restrict__ work, const int* __restrict__ nwork,
    float* __restrict__ ybuf) {
  int y = blockIdx.y;
  if (y >= *nwork) return;
  int wk = work[y];
  int e = wk >> 8, mt = wk & 255, nt = blockIdx.x;
  int hb = base[e];
  const short* wdE = wd + (size_t)e * 2097152;

  __shared__ short lds[32768];

  int tid = threadIdx.x, lane = tid & 63, wid = tid >> 6;
  int fr = lane & 15, q4r = lane >> 4;
  int wr = wid >> 1, wc = wid & 1;

  size_t aOff[2], bOff[2];
#pragma unroll
  for (int c = 0; c < 2; ++c) {
    int g = c * 4 + wid;
    aOff[c] = (size_t)(hb + mt * 128 + g * 16 + fr) * HDIM + q4r * 8;
    bOff[c] = ((size_t)(nt * 8 + g) * 64) * 512 + lane * 8;
  }

  auto stageD = [&](int tt) {
    int bb = (tt & 1) * 16384;
#pragma unroll
    for (int c = 0; c < 2; ++c) {
      int g = c * 4 + wid;
#pragma unroll
      for (int k32 = 0; k32 < 2; ++k32) {
        gload16(hbuf + aOff[c] + tt * 64 + k32 * 32,
                &lds[bb + (k32 * 8 + g) * 512 + lane * 8]);
        gload16(wdE + bOff[c] + (size_t)(tt * 2 + k32) * 512,
                &lds[bb + 8192 + (k32 * 8 + g) * 512 + lane * 8]);
      }
    }
  };

  f32x4 acc[4][4] = {};

  stageD(0);
#pragma unroll 1
  for (int t = 0; t < 32; ++t) {
    WAITVM(0);
    BARX();
    if (t < 31) stageD(t + 1);
    const short* bufp = &lds[(t & 1) * 16384];
#pragma unroll
    for (int k32 = 0; k32 < 2; ++k32) {
      bf16x8 af[4], bf[4];
#pragma unroll
      for (int m = 0; m < 4; ++m)
        af[m] = *(const bf16x8*)&bufp[(k32 * 8 + wr * 4 + m) * 512 + lane * 8];
#pragma unroll
      for (int n = 0; n < 4; ++n)
        bf[n] = *(const bf16x8*)&bufp[8192 + (k32 * 8 + wc * 4 + n) * 512 + lane * 8];
      __builtin_amdgcn_s_setprio(1);
#pragma unroll
      for (int m = 0; m < 4; ++m)
#pragma unroll
        for (int n = 0; n < 4; ++n)
          acc[m][n] = __builtin_amdgcn_mfma_f32_16x16x32_bf16(af[m], bf[n], acc[m][n], 0, 0, 0);
      __builtin_amdgcn_s_setprio(0);
    }
  }

#pragma unroll
  for (int m = 0; m < 4; ++m) {
#pragma unroll
    for (int n = 0; n < 4; ++n) {
      int col = nt * 128 + wc * 64 + n * 16 + fr;
      f32x4 a = acc[m][n];
#pragma unroll
      for (int j = 0; j < 4; ++j) {
        int row = mt * 128 + wr * 64 + m * 16 + q4r * 4 + j;
        ybuf[(size_t)(hb + row) * DMODEL + col] = a[j];
      }
    }
  }
}

// ------------ gather: out[t] = w0*y[p0] + w1*y[p1] + y[shared+t] ------------
__global__ __launch_bounds__(256) void gather_kernel(
    const float* __restrict__ ybuf, const int* __restrict__ tokpos,
    const float* __restrict__ wtok, const int* __restrict__ base,
    float* __restrict__ out) {
  int t = blockIdx.x, c4 = threadIdx.x;
  int p0 = tokpos[2 * t], p1 = tokpos[2 * t + 1];
  float w0 = wtok[2 * t], w1 = wtok[2 * t + 1];
  size_t r0 = (size_t)(base[p0 >> 12] + (p0 & 4095)) * DMODEL;
  size_t r1 = (size_t)(base[p1 >> 12] + (p1 & 4095)) * DMODEL;
  size_t rs = (size_t)(base[8] + t) * DMODEL;
  float4 v0 = *(const float4*)(ybuf + r0 + c4 * 4);
  float4 v1 = *(const float4*)(ybuf + r1 + c4 * 4);
  float4 vs = *(const float4*)(ybuf + rs + c4 * 4);
  float4 o;
  o.x = w0 * v0.x + w1 * v1.x + vs.x;
  o.y = w0 * v0.y + w1 * v1.y + vs.y;
  o.z = w0 * v0.z + w1 * v1.z + vs.z;
  o.w = w0 * v0.w + w1 * v1.w + vs.w;
  *(float4*)(out + (size_t)t * DMODEL + c4 * 4) = o;
}

extern "C" void kernel_launch(void* const* d_in, const int* in_sizes, int n_in,
                              void* d_out, int out_size, void* d_ws, size_t ws_size,
                              hipStream_t stream) {
  const float* x   = (const float*)d_in[0];
  const float* Wr  = (const float*)d_in[1];
  const float* w1  = (const float*)d_in[2];
  const float* w2  = (const float*)d_in[3];
  const float* w3  = (const float*)d_in[4];
  const float* w1s = (const float*)d_in[5];
  const float* w2s = (const float*)d_in[6];
  const float* w3s = (const float*)d_in[7];
  float* out = (float*)d_out;

  char* ws = (char*)d_ws;
  const size_t HBUF_OFF = 0;                        // 14336*2048 bf16 = 58720256
  const size_t XB_OFF   = 58720256;                 // 4096*1024 bf16 = 8388608
  const size_t WB_OFF   = XB_OFF + 8388608;         // 9*4M shorts = 75497472
  const size_t WD_OFF   = WB_OFF + 75497472;        // 9*2M shorts = 37748736
  const size_t PERM_OFF = WD_OFF + 37748736;        // 8*4096 int
  const size_t TP_OFF   = PERM_OFF + 131072;        // 8192 int
  const size_t WT_OFF   = TP_OFF + 32768;           // 8192 float
  const size_t CTRL_OFF = WT_OFF + 32768;           // 256 B
  const size_t W256_OFF = CTRL_OFF + 256;
  const size_t W128_OFF = W256_OFF + 1024;

  unsigned short* hbuf = (unsigned short*)(ws + HBUF_OFF);
  short* xb = (short*)(ws + XB_OFF);
  short* wB = (short*)(ws + WB_OFF);
  short* wd = (short*)(ws + WD_OFF);
  float* ybuf = (float*)(ws + WB_OFF);              // overlays wB (dead after upgate)
  int*   perm   = (int*)(ws + PERM_OFF);
  int*   tokpos = (int*)(ws + TP_OFF);
  float* wtok   = (float*)(ws + WT_OFF);
  int*   cursor = (int*)(ws + CTRL_OFF);
  int*   cnt1   = (int*)(ws + CTRL_OFF + 64);
  float* psum   = (float*)(ws + CTRL_OFF + 128);
  int*   base   = (int*)(ws + CTRL_OFF + 192);
  int*   n256   = (int*)(ws + CTRL_OFF + 240);
  int*   n128   = (int*)(ws + CTRL_OFF + 244);
  int*   work256 = (int*)(ws + W256_OFF);
  int*   work128 = (int*)(ws + W128_OFF);

  hipMemsetAsync(ws + CTRL_OFF, 0, 256, stream);

  router_kernel<<<1024, 256, 0, stream>>>(x, Wr, cursor, cnt1, psum, perm,
                                          tokpos, wtok, xb);
  finalize_kernel<<<1, 64, 0, stream>>>(cursor, cnt1, psum, base,
                                        work256, work128, n256, n128,
                                        out + (size_t)T_TOK * DMODEL);
  convert_w<<<27648, 256, 0, stream>>>(w1, w3, w1s, w3s, w2, w2s, wB, wd);
  gemm_upgate8<<<dim3(16, 64), 512, 0, stream>>>(xb, wB, cursor, base,
                                                 work256, n256, perm, hbuf);
  gemm_down<<<dim3(8, 128), 256, 0, stream>>>(hbuf, wd, cursor, base,
                                              work128, n128, ybuf);
  gather_kernel<<<4096, 256, 0, stream>>>(ybuf, tokpos, wtok, base, out);
}

// Round 8
// 368.989 us; speedup vs baseline: 1.6858x; 1.0929x over previous
//
#include <hip/hip_runtime.h>
#include <hip/hip_bf16.h>
#include <cstdint>

#define T_TOK 4096
#define DMODEL 1024
#define HDIM 2048

typedef short bf16x8 __attribute__((ext_vector_type(8)));
typedef float f32x4 __attribute__((ext_vector_type(4)));
typedef uint32_t u32x4 __attribute__((ext_vector_type(4)));

#define WAITVM(N) asm volatile("s_waitcnt vmcnt(" #N ")" ::: "memory")
#define BARX() asm volatile("s_barrier" ::: "memory")

__device__ __forceinline__ uint32_t cvt_pk_bf16(float lo, float hi) {
  uint32_t d;
  asm("v_cvt_pk_bf16_f32 %0, %1, %2" : "=v"(d) : "v"(lo), "v"(hi));
  return d;
}
__device__ __forceinline__ unsigned short f2bf(float f) {
  uint32_t d;
  asm("v_cvt_pk_bf16_f32 %0, %1, %1" : "=v"(d) : "v"(f));
  return (unsigned short)d;
}
// fast exact-erf GELU: Abramowitz-Stegun 7.1.26, |err| <= 1.5e-7
__device__ __forceinline__ float gelu_fast(float v) {
  float z = v * 0.70710678118654752f;
  float az = fabsf(z);
  float t = __frcp_rn(1.0f + 0.3275911f * az);
  float poly = ((((1.061405429f * t - 1.453152027f) * t + 1.421413741f) * t
                 - 0.284496736f) * t + 0.254829592f) * t;
  float er = 1.0f - poly * __expf(-z * z);
  er = (z < 0.f) ? -er : er;
  return 0.5f * v * (1.0f + er);
}
__device__ __forceinline__ void gload16(const void* g, void* lds) {
  __builtin_amdgcn_global_load_lds((const __attribute__((address_space(1))) void*)g,
                                   (__attribute__((address_space(3))) void*)lds, 16, 0, 0);
}
__device__ __forceinline__ u32x4 pk8(const float* s) {
  float4 v0 = ((const float4*)s)[0], v1 = ((const float4*)s)[1];
  u32x4 p = {cvt_pk_bf16(v0.x, v0.y), cvt_pk_bf16(v0.z, v0.w),
             cvt_pk_bf16(v1.x, v1.y), cvt_pk_bf16(v1.z, v1.w)};
  return p;
}

// ---------------- conversions (fragment-major bf16) ----------------
// wB per expert (upgate, u/g col-interleaved): [nf:256][k32:32][lane:64][8]
// wd per expert (down): [d16:64][h32:64][lane:64][8]
__global__ __launch_bounds__(256) void convert_w(
    const float* __restrict__ w1, const float* __restrict__ w3,
    const float* __restrict__ w1s, const float* __restrict__ w3s,
    const float* __restrict__ w2, const float* __restrict__ w2s,
    short* __restrict__ wB, short* __restrict__ wd) {
  int bid = blockIdx.x;
  if (bid < 18432) {
    int id = bid * 256 + threadIdx.x;
    int e = id >> 19, rem = id & 524287;
    int nf = rem >> 11, k32 = (rem >> 6) & 31, ln = rem & 63;
    int h = (nf >> 1) * 16 + (ln & 15);
    size_t so = (size_t)h * DMODEL + k32 * 32 + (ln >> 4) * 8;
    const float* src = (nf & 1)
        ? ((e < 8) ? w3 + (size_t)e * 2097152 + so : w3s + so)
        : ((e < 8) ? w1 + (size_t)e * 2097152 + so : w1s + so);
    *(u32x4*)(wB + (size_t)id * 8) = pk8(src);
  } else {
    int id = (bid - 18432) * 256 + threadIdx.x;
    int e = id >> 18, rem = id & 262143;
    int d16 = rem >> 12, h32 = (rem >> 6) & 63, ln = rem & 63;
    size_t so = (size_t)(d16 * 16 + (ln & 15)) * HDIM + h32 * 32 + (ln >> 4) * 8;
    const float* s2 = (e < 8) ? w2 + (size_t)e * 2097152 + so : w2s + so;
    *(u32x4*)(wd + (size_t)id * 8) = pk8(s2);
  }
}

// ---------------- router: one wave per token; also emits xb + token routing ------
__global__ __launch_bounds__(256) void router_kernel(
    const float* __restrict__ x, const float* __restrict__ Wr,
    int* __restrict__ cursor, int* __restrict__ cnt1,
    float* __restrict__ psum, int* __restrict__ perm,
    int* __restrict__ tokpos, float* __restrict__ wtok,
    short* __restrict__ xb) {
  __shared__ float4 sW[8 * 256];
  __shared__ float sP[8];
  int tid = threadIdx.x;
  const float4* W4 = (const float4*)Wr;
  for (int i = tid; i < 2048; i += 256) sW[i] = W4[i];
  if (tid < 8) sP[tid] = 0.f;
  __syncthreads();

  int lane = tid & 63, wid = tid >> 6;
  int t = blockIdx.x * 4 + wid;
  float acc[8] = {0.f, 0.f, 0.f, 0.f, 0.f, 0.f, 0.f, 0.f};
  const float4* x4 = (const float4*)(x + (size_t)t * DMODEL);
#pragma unroll
  for (int it = 0; it < 4; ++it) {
    float4 xv = x4[it * 64 + lane];
    uint2 pk = {cvt_pk_bf16(xv.x, xv.y), cvt_pk_bf16(xv.z, xv.w)};
    *(uint2*)(xb + (size_t)t * DMODEL + it * 256 + lane * 4) = pk;
#pragma unroll
    for (int e = 0; e < 8; ++e) {
      float4 wv = sW[e * 256 + it * 64 + lane];
      acc[e] += xv.x * wv.x + xv.y * wv.y + xv.z * wv.z + xv.w * wv.w;
    }
  }
#pragma unroll
  for (int e = 0; e < 8; ++e)
    for (int off = 32; off; off >>= 1) acc[e] += __shfl_xor(acc[e], off);

  float mx = acc[0];
#pragma unroll
  for (int e = 1; e < 8; ++e) mx = fmaxf(mx, acc[e]);
  float ex[8], s = 0.f;
#pragma unroll
  for (int e = 0; e < 8; ++e) { ex[e] = expf(acc[e] - mx); s += ex[e]; }
  float inv = 1.f / s;
  int e0 = 0;
#pragma unroll
  for (int e = 1; e < 8; ++e) if (acc[e] > acc[e0]) e0 = e;
  int e1 = (e0 == 0) ? 1 : 0;
#pragma unroll
  for (int e = 0; e < 8; ++e) if (e != e0 && acc[e] > acc[e1]) e1 = e;

  if (lane == 0) {
#pragma unroll
    for (int e = 0; e < 8; ++e) atomicAdd(&sP[e], ex[e] * inv);
    atomicAdd(&cnt1[e0], 1);
    int s0 = atomicAdd(&cursor[e0], 1);
    perm[e0 * 4096 + s0] = t;
    int s1 = atomicAdd(&cursor[e1], 1);
    perm[e1 * 4096 + s1] = t;
    tokpos[2 * t] = (e0 << 12) | s0;
    tokpos[2 * t + 1] = (e1 << 12) | s1;
    wtok[2 * t] = ex[e0] * inv;
    wtok[2 * t + 1] = ex[e1] * inv;
  }
  __syncthreads();
  if (tid < 8) atomicAdd(&psum[tid], sP[tid]);
}

// ------- finalize: 256-aligned bases + worklist + aux loss -------
__global__ void finalize_kernel(const int* __restrict__ cursor,
                                const int* __restrict__ cnt1,
                                const float* __restrict__ psum,
                                int* __restrict__ base,
                                int* __restrict__ work256, int* __restrict__ n256,
                                float* __restrict__ aux_out) {
  if (threadIdx.x == 0) {
    int b = 0, a = 0;
    for (int e = 0; e < 9; ++e) {
      int c = (e < 8) ? cursor[e] : 4096;
      base[e] = b;
      int t2 = (c + 255) >> 8;
      for (int mt = 0; mt < t2; ++mt) work256[a++] = (e << 8) | mt;
      b += t2 << 8;
    }
    *n256 = a;
    float aux = 0.f;
    for (int e = 0; e < 8; ++e)
      aux += ((float)cnt1[e] * (1.f / T_TOK)) * (psum[e] * (1.f / T_TOK));
    aux_out[0] = 0.01f * 8.f * aux;
  }
}

// ============ 256x256 up+gate GEMM: 4-phase counted-vmcnt pipeline, BK=64 ======
// LDS buf (32768 shorts): A[(k32*16+g)*512+lane*8] | B at +16384 same indexing.
// Chunks per K-tile: c0=A(k0) c1=B(k0) c2=A(k1) c3=B(k1), 2 gloads each.
__global__ __launch_bounds__(512) void gemm_upgate8(
    const short* __restrict__ xb, const short* __restrict__ wB,
    const int* __restrict__ cursor, const int* __restrict__ base,
    const int* __restrict__ work, const int* __restrict__ nwork,
    const int* __restrict__ perm, unsigned short* __restrict__ hbuf) {
  int y = blockIdx.y;
  if (y >= *nwork) return;
  int wk = work[y];
  int e = wk >> 8, mt = wk & 255, nt = blockIdx.x;
  int cnt = (e < 8) ? cursor[e] : 4096;
  int hb = base[e];
  const short* wE = wB + (size_t)e * 4194304;

  __shared__ short lds[65536];

  int tid = threadIdx.x, lane = tid & 63, wid = tid >> 6;
  int wm = wid >> 2, wn = wid & 3;
  int fr = lane & 15, q4r = lane >> 4;

  size_t aOff[2];
#pragma unroll
  for (int c = 0; c < 2; ++c) {
    int g = c * 8 + wid;
    int slot = mt * 256 + g * 16 + fr;
    int tok = (e == 8) ? slot : ((slot < cnt) ? perm[e * 4096 + slot] : 0);
    aOff[c] = (size_t)tok * DMODEL + q4r * 8;
  }
  size_t bOff[2];
#pragma unroll
  for (int c = 0; c < 2; ++c)
    bOff[c] = ((size_t)(nt * 16 + c * 8 + wid) * 32) * 512 + lane * 8;

#define UPG_STAGE_A(tt, k32)                                                   \
  { int bb_ = ((tt) & 1) * 32768;                                              \
    gload16(xb + aOff[0] + (tt) * 64 + (k32) * 32,                             \
            &lds[bb_ + ((k32) * 16 + wid) * 512 + lane * 8]);                  \
    gload16(xb + aOff[1] + (tt) * 64 + (k32) * 32,                             \
            &lds[bb_ + ((k32) * 16 + 8 + wid) * 512 + lane * 8]); }
#define UPG_STAGE_B(tt, k32)                                                   \
  { int bb_ = ((tt) & 1) * 32768;                                              \
    gload16(wE + bOff[0] + (size_t)((tt) * 2 + (k32)) * 512,                   \
            &lds[bb_ + 16384 + ((k32) * 16 + wid) * 512 + lane * 8]);          \
    gload16(wE + bOff[1] + (size_t)((tt) * 2 + (k32)) * 512,                   \
            &lds[bb_ + 16384 + ((k32) * 16 + 8 + wid) * 512 + lane * 8]); }
#define UPG_READA(k32, mh)                                                     \
  { _Pragma("unroll") for (int i = 0; i < 4; ++i)                              \
      af[i] = *(const bf16x8*)&lds[bb + ((k32) * 16 + wm * 8 + (mh) * 4 + i) * \
                                       512 + lane * 8]; }
#define UPG_READB(k32)                                                         \
  { _Pragma("unroll") for (int n = 0; n < 4; ++n)                              \
      bf[n] = *(const bf16x8*)&lds[bb + 16384 + ((k32) * 16 + wn * 4 + n) *    \
                                       512 + lane * 8]; }
#define UPG_MFMA(mh)                                                           \
  { __builtin_amdgcn_s_setprio(1);                                             \
    _Pragma("unroll") for (int i = 0; i < 4; ++i)                              \
      _Pragma("unroll") for (int n = 0; n < 4; ++n)                            \
        acc[(mh) * 4 + i][n] = __builtin_amdgcn_mfma_f32_16x16x32_bf16(        \
            af[i], bf[n], acc[(mh) * 4 + i][n], 0, 0, 0);                      \
    __builtin_amdgcn_s_setprio(0); }

  f32x4 acc[8][4] = {};
  bf16x8 af[4], bf[4];

  // prologue: tile 0 fully issued (8 loads), certify c0,c1 resident
  UPG_STAGE_A(0, 0); UPG_STAGE_B(0, 0); UPG_STAGE_A(0, 1); UPG_STAGE_B(0, 1);
  WAITVM(4); BARX();

#pragma unroll 1
  for (int t = 0; t < 15; ++t) {
    const int bb = (t & 1) * 32768;
    // P0: (k0, mh0)
    UPG_READA(0, 0); UPG_READB(0); UPG_STAGE_A(t + 1, 0);
    BARX(); UPG_MFMA(0); BARX();
    // P1: (k0, mh1)
    UPG_READA(0, 1); UPG_STAGE_B(t + 1, 0);
    BARX(); UPG_MFMA(1); WAITVM(4); BARX();
    // P2: (k1, mh0)
    UPG_READA(1, 0); UPG_READB(1); UPG_STAGE_A(t + 1, 1);
    BARX(); UPG_MFMA(0); BARX();
    // P3: (k1, mh1)
    UPG_READA(1, 1); UPG_STAGE_B(t + 1, 1);
    BARX(); UPG_MFMA(1); WAITVM(4); BARX();
  }
  {  // t = 15 (no prefetch)
    const int bb = 32768;
    UPG_READA(0, 0); UPG_READB(0); BARX(); UPG_MFMA(0); BARX();
    UPG_READA(0, 1); BARX(); UPG_MFMA(1); WAITVM(0); BARX();
    UPG_READA(1, 0); UPG_READB(1); BARX(); UPG_MFMA(0); BARX();
    UPG_READA(1, 1); UPG_MFMA(1);
  }

  // epilogue: pair even/odd n-frags (u, g) -> gelu(u)*g
#pragma unroll
  for (int m = 0; m < 8; ++m) {
#pragma unroll
    for (int p = 0; p < 2; ++p) {
      f32x4 u = acc[m][2 * p], g = acc[m][2 * p + 1];
      int hcol = (nt * 8 + wn * 2 + p) * 16 + fr;
#pragma unroll
      for (int j = 0; j < 4; ++j) {
        int sl = mt * 256 + wm * 128 + m * 16 + q4r * 4 + j;
        float hv = (sl < cnt) ? gelu_fast(u[j]) * g[j] : 0.f;
        hbuf[(size_t)(hb + sl) * HDIM + hcol] = f2bf(hv);
      }
    }
  }
}

// ============ down GEMM: 256x256, same 4-phase pipeline, 32 K-tiles ============
__global__ __launch_bounds__(512) void gemm_down8(
    const unsigned short* __restrict__ hbuf, const short* __restrict__ wd,
    const int* __restrict__ base,
    const int* __restrict__ work, const int* __restrict__ nwork,
    float* __restrict__ ybuf) {
  int y = blockIdx.y;
  if (y >= *nwork) return;
  int wk = work[y];
  int e = wk >> 8, mt = wk & 255, nt = blockIdx.x;
  int hb = base[e];
  const short* wdE = wd + (size_t)e * 2097152;

  __shared__ short lds[65536];

  int tid = threadIdx.x, lane = tid & 63, wid = tid >> 6;
  int wm = wid >> 2, wn = wid & 3;
  int fr = lane & 15, q4r = lane >> 4;

  size_t aOff[2];
#pragma unroll
  for (int c = 0; c < 2; ++c)
    aOff[c] = (size_t)(hb + mt * 256 + (c * 8 + wid) * 16 + fr) * HDIM + q4r * 8;
  size_t bOff[2];
#pragma unroll
  for (int c = 0; c < 2; ++c)
    bOff[c] = ((size_t)(nt * 16 + c * 8 + wid) * 64) * 512 + lane * 8;

#define DWN_STAGE_A(tt, k32)                                                   \
  { int bb_ = ((tt) & 1) * 32768;                                              \
    gload16(hbuf + aOff[0] + (tt) * 64 + (k32) * 32,                           \
            &lds[bb_ + ((k32) * 16 + wid) * 512 + lane * 8]);                  \
    gload16(hbuf + aOff[1] + (tt) * 64 + (k32) * 32,                           \
            &lds[bb_ + ((k32) * 16 + 8 + wid) * 512 + lane * 8]); }
#define DWN_STAGE_B(tt, k32)                                                   \
  { int bb_ = ((tt) & 1) * 32768;                                              \
    gload16(wdE + bOff[0] + (size_t)((tt) * 2 + (k32)) * 512,                  \
            &lds[bb_ + 16384 + ((k32) * 16 + wid) * 512 + lane * 8]);          \
    gload16(wdE + bOff[1] + (size_t)((tt) * 2 + (k32)) * 512,                  \
            &lds[bb_ + 16384 + ((k32) * 16 + 8 + wid) * 512 + lane * 8]); }

  f32x4 acc[8][4] = {};
  bf16x8 af[4], bf[4];

  DWN_STAGE_A(0, 0); DWN_STAGE_B(0, 0); DWN_STAGE_A(0, 1); DWN_STAGE_B(0, 1);
  WAITVM(4); BARX();

#pragma unroll 1
  for (int t = 0; t < 31; ++t) {
    const int bb = (t & 1) * 32768;
    UPG_READA(0, 0); UPG_READB(0); DWN_STAGE_A(t + 1, 0);
    BARX(); UPG_MFMA(0); BARX();
    UPG_READA(0, 1); DWN_STAGE_B(t + 1, 0);
    BARX(); UPG_MFMA(1); WAITVM(4); BARX();
    UPG_READA(1, 0); UPG_READB(1); DWN_STAGE_A(t + 1, 1);
    BARX(); UPG_MFMA(0); BARX();
    UPG_READA(1, 1); DWN_STAGE_B(t + 1, 1);
    BARX(); UPG_MFMA(1); WAITVM(4); BARX();
  }
  {  // t = 31
    const int bb = 32768;
    UPG_READA(0, 0); UPG_READB(0); BARX(); UPG_MFMA(0); BARX();
    UPG_READA(0, 1); BARX(); UPG_MFMA(1); WAITVM(0); BARX();
    UPG_READA(1, 0); UPG_READB(1); BARX(); UPG_MFMA(0); BARX();
    UPG_READA(1, 1); UPG_MFMA(1);
  }

#pragma unroll
  for (int m = 0; m < 8; ++m) {
#pragma unroll
    for (int n = 0; n < 4; ++n) {
      int col = (nt * 16 + wn * 4 + n) * 16 + fr;
      f32x4 a = acc[m][n];
#pragma unroll
      for (int j = 0; j < 4; ++j) {
        int row = mt * 256 + wm * 128 + m * 16 + q4r * 4 + j;
        ybuf[(size_t)(hb + row) * DMODEL + col] = a[j];
      }
    }
  }
}

// ------------ gather: out[t] = w0*y[p0] + w1*y[p1] + y[shared+t] ------------
__global__ __launch_bounds__(256) void gather_kernel(
    const float* __restrict__ ybuf, const int* __restrict__ tokpos,
    const float* __restrict__ wtok, const int* __restrict__ base,
    float* __restrict__ out) {
  int t = blockIdx.x, c4 = threadIdx.x;
  int p0 = tokpos[2 * t], p1 = tokpos[2 * t + 1];
  float w0 = wtok[2 * t], w1 = wtok[2 * t + 1];
  size_t r0 = (size_t)(base[p0 >> 12] + (p0 & 4095)) * DMODEL;
  size_t r1 = (size_t)(base[p1 >> 12] + (p1 & 4095)) * DMODEL;
  size_t rs = (size_t)(base[8] + t) * DMODEL;
  float4 v0 = *(const float4*)(ybuf + r0 + c4 * 4);
  float4 v1 = *(const float4*)(ybuf + r1 + c4 * 4);
  float4 vs = *(const float4*)(ybuf + rs + c4 * 4);
  float4 o;
  o.x = w0 * v0.x + w1 * v1.x + vs.x;
  o.y = w0 * v0.y + w1 * v1.y + vs.y;
  o.z = w0 * v0.z + w1 * v1.z + vs.z;
  o.w = w0 * v0.w + w1 * v1.w + vs.w;
  *(float4*)(out + (size_t)t * DMODEL + c4 * 4) = o;
}

extern "C" void kernel_launch(void* const* d_in, const int* in_sizes, int n_in,
                              void* d_out, int out_size, void* d_ws, size_t ws_size,
                              hipStream_t stream) {
  const float* x   = (const float*)d_in[0];
  const float* Wr  = (const float*)d_in[1];
  const float* w1  = (const float*)d_in[2];
  const float* w2  = (const float*)d_in[3];
  const float* w3  = (const float*)d_in[4];
  const float* w1s = (const float*)d_in[5];
  const float* w2s = (const float*)d_in[6];
  const float* w3s = (const float*)d_in[7];
  float* out = (float*)d_out;

  char* ws = (char*)d_ws;
  const size_t HBUF_OFF = 0;                        // 14336*2048 bf16 = 58720256
  const size_t XB_OFF   = 58720256;                 // 4096*1024 bf16 = 8388608
  const size_t WB_OFF   = XB_OFF + 8388608;         // 9*4M shorts = 75497472
  const size_t WD_OFF   = WB_OFF + 75497472;        // 9*2M shorts = 37748736
  const size_t PERM_OFF = WD_OFF + 37748736;        // 8*4096 int
  const size_t TP_OFF   = PERM_OFF + 131072;        // 8192 int
  const size_t WT_OFF   = TP_OFF + 32768;           // 8192 float
  const size_t CTRL_OFF = WT_OFF + 32768;           // 256 B
  const size_t W256_OFF = CTRL_OFF + 256;

  unsigned short* hbuf = (unsigned short*)(ws + HBUF_OFF);
  short* xb = (short*)(ws + XB_OFF);
  short* wB = (short*)(ws + WB_OFF);
  short* wd = (short*)(ws + WD_OFF);
  float* ybuf = (float*)(ws + WB_OFF);              // overlays wB (dead after upgate)
  int*   perm   = (int*)(ws + PERM_OFF);
  int*   tokpos = (int*)(ws + TP_OFF);
  float* wtok   = (float*)(ws + WT_OFF);
  int*   cursor = (int*)(ws + CTRL_OFF);
  int*   cnt1   = (int*)(ws + CTRL_OFF + 64);
  float* psum   = (float*)(ws + CTRL_OFF + 128);
  int*   base   = (int*)(ws + CTRL_OFF + 192);
  int*   n256   = (int*)(ws + CTRL_OFF + 240);
  int*   work256 = (int*)(ws + W256_OFF);

  hipMemsetAsync(ws + CTRL_OFF, 0, 256, stream);

  router_kernel<<<1024, 256, 0, stream>>>(x, Wr, cursor, cnt1, psum, perm,
                                          tokpos, wtok, xb);
  finalize_kernel<<<1, 64, 0, stream>>>(cursor, cnt1, psum, base,
                                        work256, n256,
                                        out + (size_t)T_TOK * DMODEL);
  convert_w<<<27648, 256, 0, stream>>>(w1, w3, w1s, w3s, w2, w2s, wB, wd);
  gemm_upgate8<<<dim3(16, 64), 512, 0, stream>>>(xb, wB, cursor, base,
                                                 work256, n256, perm, hbuf);
  gemm_down8<<<dim3(4, 64), 512, 0, stream>>>(hbuf, wd, base,
                                              work256, n256, ybuf);
  gather_kernel<<<4096, 256, 0, stream>>>(ybuf, tokpos, wtok, base, out);
}